// Round 15
// baseline (149.151 us; speedup 1.0000x reference)
//
#include <hip/hip_runtime.h>
#include <hip/hip_bf16.h>
#include <math.h>

#define B_ 4
#define N_ 256
#define D_ 128
#define H_ 256
#define K_ 8

typedef __attribute__((ext_vector_type(8))) short short8;
typedef __attribute__((ext_vector_type(4))) float f32x4;

__device__ __forceinline__ unsigned short f2bf(float x) {
    union { __hip_bfloat16 h; unsigned short s; } u;
    u.h = __float2bfloat16(x);
    return u.s;
}
__device__ __forceinline__ float bf2f(unsigned short b) {
    unsigned v = ((unsigned)b) << 16;
    return __builtin_bit_cast(float, v);
}
__device__ __forceinline__ unsigned pk2(float x, float y) {
    union { __hip_bfloat162 h; unsigned u; } c;
    c.h = __float22bfloat162_rn(float2{x, y});
    return c.u;
}

// K0 (fused): blocks 0..255: avec/bvec; blocks 256..383: Wt transpose. (Unchanged.)
__global__ __launch_bounds__(256) void pre_kernel(
    const float* __restrict__ s, const float* __restrict__ W1,
    const float* __restrict__ b1,
    float* __restrict__ avec, float* __restrict__ bvec,
    unsigned short* __restrict__ Wt)
{
    int blk = blockIdx.x;
    int t = threadIdx.x;
    if (blk < 256) {
        int bi0 = blk * 4;
        __shared__ float s4[4][D_];
        for (int idx = t; idx < 4 * D_; idx += 256) {
            int r = idx >> 7, d = idx & 127;
            s4[r][d] = s[(size_t)(bi0 + r) * D_ + d];
        }
        __syncthreads();
        float aA[4], aB[4];
        float b1v = b1[t];
        #pragma unroll
        for (int r = 0; r < 4; ++r) { aA[r] = b1v; aB[r] = 0.f; }
        for (int d = 0; d < D_; ++d) {
            float wa = W1[(size_t)d * H_ + t];
            float wb = W1[(size_t)(D_ + d) * H_ + t];
            #pragma unroll
            for (int r = 0; r < 4; ++r) {
                aA[r] = fmaf(s4[r][d], wa, aA[r]);
                aB[r] = fmaf(s4[r][d], wb, aB[r]);
            }
        }
        #pragma unroll
        for (int r = 0; r < 4; ++r) {
            avec[(size_t)(bi0 + r) * H_ + t] = aA[r];
            bvec[(size_t)(bi0 + r) * H_ + t] = aB[r];
        }
    } else {
        int e = (blk - 256) * 256 + t;
        int h = e >> 7, d = e & 127;
        Wt[e] = f2bf(W1[(size_t)(2 * D_ + d) * H_ + h]);
    }
}

// K1 v4: block = (b, jt of 64 j, ic of 16 i). 256 blocks = 1/CU, 512 thr = 8 waves.
// (Unchanged — left the top-5.)
__global__ __launch_bounds__(512, 2) void approx_scores(
    const float* __restrict__ s, const unsigned short* __restrict__ Wt,
    const float* __restrict__ W2, const float* __restrict__ b2,
    const float* __restrict__ avec, const float* __restrict__ bvec,
    unsigned short* __restrict__ ascu)
{
    int blk = blockIdx.x;              // 256 = b(4) x jt(4) x ic(16)
    int b   = blk >> 6;
    int jtb = ((blk >> 4) & 3) * 64;
    int i0  = (blk & 15) * 16;
    int t = threadIdx.x;
    int lane = t & 63;
    int w = __builtin_amdgcn_readfirstlane(t >> 6);    // wave 0..7 -> 32-h slice
    int l15 = lane & 15, quad = lane >> 4;

    __shared__ __align__(16) short Pl[2][64 * 128];    // 32 KB (dbuf)
    __shared__ __align__(16) float si_all[16][D_];     // 8 KB
    __shared__ float partial[2][8][64];                // 4 KB

    const float* sB = s + (size_t)b * N_ * D_;

    {
        int ii = t >> 5, dq = t & 31;
        *(float4*)&si_all[ii][dq * 4] =
            *(const float4*)(sB + (size_t)(i0 + ii) * D_ + dq * 4);
    }

    short8 Wreg[2][4];
    #pragma unroll
    for (int mi = 0; mi < 2; ++mi)
        #pragma unroll
        for (int dk = 0; dk < 4; ++dk)
            Wreg[mi][dk] = *(const short8*)(
                Wt + (size_t)(w * 32 + mi * 16 + l15) * D_ + dk * 32 + quad * 8);
    float bvr[2][4][4];
    float w2r[2][4];
    #pragma unroll
    for (int mi = 0; mi < 2; ++mi) {
        int hq = w * 32 + mi * 16 + quad * 4;
        #pragma unroll
        for (int r = 0; r < 4; ++r)
            w2r[mi][r] = W2[hq + r];
        #pragma unroll
        for (int nj = 0; nj < 4; ++nj)
            #pragma unroll
            for (int r = 0; r < 4; ++r)
                bvr[mi][nj][r] = bvec[((size_t)(b * N_ + jtb + nj * 16 + l15)) * H_
                                      + hq + r];
    }
    float b2v = b2[0];
    __syncthreads();

    {
        int row = t >> 3, seg = t & 7;
        const float* sj = sB + (size_t)(jtb + row) * D_ + seg * 16;
        float4 a0 = ((const float4*)sj)[0], a1 = ((const float4*)sj)[1];
        float4 a2 = ((const float4*)sj)[2], a3 = ((const float4*)sj)[3];
        const float* si = &si_all[0][seg * 16];
        float4 s0 = ((const float4*)si)[0], s1 = ((const float4*)si)[1];
        float4 s2 = ((const float4*)si)[2], s3 = ((const float4*)si)[3];
        uint4 v0, v1;
        v0.x = pk2(a0.x * s0.x, a0.y * s0.y); v0.y = pk2(a0.z * s0.z, a0.w * s0.w);
        v0.z = pk2(a1.x * s1.x, a1.y * s1.y); v0.w = pk2(a1.z * s1.z, a1.w * s1.w);
        v1.x = pk2(a2.x * s2.x, a2.y * s2.y); v1.y = pk2(a2.z * s2.z, a2.w * s2.w);
        v1.z = pk2(a3.x * s3.x, a3.y * s3.y); v1.w = pk2(a3.z * s3.z, a3.w * s3.w);
        int pc0 = (seg * 2) ^ (row & 15), pc1 = (seg * 2 + 1) ^ (row & 15);
        *(uint4*)&Pl[0][row * 128 + pc0 * 8] = v0;
        *(uint4*)&Pl[0][row * 128 + pc1 * 8] = v1;
    }
    __syncthreads();

    #pragma unroll 1
    for (int i = 0; i < 16; ++i) {
        int cur = i & 1;
        if (w == 0 && i > 0) {
            float sum = b2v;
            #pragma unroll
            for (int ww = 0; ww < 8; ++ww) sum += partial[(i - 1) & 1][ww][lane];
            ascu[(size_t)(b * N_ + i0 + i - 1) * N_ + jtb + lane] = f2bf(sum);
        }
        float avc[2][4];
        #pragma unroll
        for (int mi = 0; mi < 2; ++mi) {
            int hq = w * 32 + mi * 16 + quad * 4;
            #pragma unroll
            for (int r = 0; r < 4; ++r)
                avc[mi][r] = avec[(size_t)(b * N_ + i0 + i) * H_ + hq + r];
        }
        f32x4 acc[2][4];
        #pragma unroll
        for (int mi = 0; mi < 2; ++mi)
            #pragma unroll
            for (int nj = 0; nj < 4; ++nj)
                acc[mi][nj] = (f32x4){0.f, 0.f, 0.f, 0.f};
        #pragma unroll
        for (int dk = 0; dk < 4; ++dk) {
            short8 Pf[4];
            #pragma unroll
            for (int nj = 0; nj < 4; ++nj) {
                int pcc = (dk * 4 + quad) ^ l15;
                Pf[nj] = *(const short8*)&Pl[cur][(nj * 16 + l15) * 128 + pcc * 8];
            }
            #pragma unroll
            for (int nj = 0; nj < 4; ++nj)
                #pragma unroll
                for (int mi = 0; mi < 2; ++mi)
                    acc[mi][nj] = __builtin_amdgcn_mfma_f32_16x16x32_bf16(
                        Wreg[mi][dk], Pf[nj], acc[mi][nj], 0, 0, 0);
        }
        if (i < 15) {
            int row = t >> 3, seg = t & 7;
            const float* sj = sB + (size_t)(jtb + row) * D_ + seg * 16;
            float4 a0 = ((const float4*)sj)[0], a1 = ((const float4*)sj)[1];
            float4 a2 = ((const float4*)sj)[2], a3 = ((const float4*)sj)[3];
            const float* si = &si_all[i + 1][seg * 16];
            float4 s0 = ((const float4*)si)[0], s1 = ((const float4*)si)[1];
            float4 s2 = ((const float4*)si)[2], s3 = ((const float4*)si)[3];
            uint4 v0, v1;
            v0.x = pk2(a0.x * s0.x, a0.y * s0.y); v0.y = pk2(a0.z * s0.z, a0.w * s0.w);
            v0.z = pk2(a1.x * s1.x, a1.y * s1.y); v0.w = pk2(a1.z * s1.z, a1.w * s1.w);
            v1.x = pk2(a2.x * s2.x, a2.y * s2.y); v1.y = pk2(a2.z * s2.z, a2.w * s2.w);
            v1.z = pk2(a3.x * s3.x, a3.y * s3.y); v1.w = pk2(a3.z * s3.z, a3.w * s3.w);
            int pc0 = (seg * 2) ^ (row & 15), pc1 = (seg * 2 + 1) ^ (row & 15);
            *(uint4*)&Pl[cur ^ 1][row * 128 + pc0 * 8] = v0;
            *(uint4*)&Pl[cur ^ 1][row * 128 + pc1 * 8] = v1;
        }
        float rs[4];
        #pragma unroll
        for (int nj = 0; nj < 4; ++nj) rs[nj] = 0.f;
        #pragma unroll
        for (int mi = 0; mi < 2; ++mi)
            #pragma unroll
            for (int nj = 0; nj < 4; ++nj)
                #pragma unroll
                for (int r = 0; r < 4; ++r) {
                    float z = acc[mi][nj][r] + avc[mi][r] + bvr[mi][nj][r];
                    rs[nj] = fmaf(fmaxf(z, 0.f), w2r[mi][r], rs[nj]);
                }
        #pragma unroll
        for (int nj = 0; nj < 4; ++nj) {
            rs[nj] += __shfl_xor(rs[nj], 16);
            rs[nj] += __shfl_xor(rs[nj], 32);
        }
        float v = (quad == 0) ? rs[0] : (quad == 1) ? rs[1] : (quad == 2) ? rs[2] : rs[3];
        partial[cur][w][lane] = v;
        __syncthreads();
    }
    if (w == 0) {
        float sum = b2v;
        #pragma unroll
        for (int ww = 0; ww < 8; ++ww) sum += partial[15 & 1][ww][lane];
        ascu[(size_t)(b * N_ + i0 + 15) * N_ + jtb + lane] = f2bf(sum);
    }
}

// K2 v5b: ONLY change vs R14: __launch_bounds__(256, 2).
// Allocator evidence across rounds: it sizes VGPRs to chase occupancy and
// spills (R11-R13 512-thr: 56 regs/40 MB; R14 256-thr bare: 80 regs/10.9 MB).
// The one proven-effective knob+shape combo is 256 threads + min-waves=2
// (approx R8->R10: 64->84 regs, spill eliminated). Budget 256 regs; kernel
// needs ~100; LDS 37 KB still permits 4 blocks/CU at 100 regs.
#define DC2 16
__global__ __launch_bounds__(256, 2) void finalize_kernel(
    const float* __restrict__ s, const float* __restrict__ W1,
    const float* __restrict__ W2, const float* __restrict__ b2,
    const float* __restrict__ avec, const float* __restrict__ bvec,
    const unsigned short* __restrict__ ascu,
    float* __restrict__ ctx, float* __restrict__ gate, float* __restrict__ w)
{
    int bi0 = blockIdx.x * 2;          // 512 blocks
    int b = bi0 >> 8;
    int t = threadIdx.x;               // 0..255

    __shared__ float asc[2][N_];                    // 2 KB
    __shared__ int cand[2][16];
    __shared__ __align__(16) float Pt[D_][32];      // 16 KB [d][pair]
    __shared__ __align__(16) float Wl[DC2][H_];     // 16 KB [d-in-chunk][h]
    __shared__ float part[32][17];                  // 2.1 KB [pair][hg]
    __shared__ float rsc[2][16];
    __shared__ int sel8[2][8];

    // --- approx scores + top-16 per row ---
    for (int e = t; e < 512; e += 256) {
        int tr = e >> 8, jj = e & 255;
        asc[tr][jj] = bf2f(ascu[(size_t)(bi0 + tr) * N_ + jj]);
    }
    __syncthreads();
    for (int e = t; e < 512; e += 256) {
        int tr = e >> 8, jj = e & 255;
        float my = asc[tr][jj];
        int rank = 0;
        #pragma unroll 8
        for (int j2 = 0; j2 < N_; ++j2) {
            float o = asc[tr][j2];
            rank += (o > my) || (o == my && j2 < jj);
        }
        if (rank < 16) cand[tr][rank] = jj;
    }
    __syncthreads();

    const float* Wc = W1 + (size_t)2 * D_ * H_;     // W1c[d][h]

    // prefetch W chunk 0 (16 rows x 256 = 1024 float4, 4/thread)
    float4 wpre[4];
    #pragma unroll
    for (int k = 0; k < 4; ++k) {
        int q = t + 256 * k;
        int dd = q >> 6, hh = (q & 63) * 4;
        wpre[k] = *(const float4*)(Wc + (size_t)dd * H_ + hh);
    }

    // build Pt[d][pair] (32 pairs)
    for (int e = t; e < 1024; e += 256) {
        int p = e & 31, dq = e >> 5;
        int r = p >> 4, c = p & 15;
        int j = cand[r][c];
        float4 sj = *(const float4*)(s + ((size_t)(b * N_ + j)) * D_ + dq * 4);
        float4 si = *(const float4*)(s + ((size_t)(bi0 + r)) * D_ + dq * 4);
        Pt[dq * 4 + 0][p] = si.x * sj.x;
        Pt[dq * 4 + 1][p] = si.y * sj.y;
        Pt[dq * 4 + 2][p] = si.z * sj.z;
        Pt[dq * 4 + 3][p] = si.w * sj.w;
    }

    // acc init: exact fp32 a_i[h] + b_j[h]
    int pg = t & 15, hg = t >> 4;                   // hg 0..15
    int h0 = hg * 16;
    float acc[2][16];
    #pragma unroll
    for (int pp = 0; pp < 2; ++pp) {
        int p = pg * 2 + pp;
        int r = p >> 4, c = p & 15;
        int j = cand[r][c];
        const float* av = avec + (size_t)(bi0 + r) * H_ + h0;
        const float* bv = bvec + ((size_t)(b * N_ + j)) * H_ + h0;
        #pragma unroll
        for (int m4 = 0; m4 < 4; ++m4) {
            float4 a4 = *(const float4*)(av + m4 * 4);
            float4 b4 = *(const float4*)(bv + m4 * 4);
            acc[pp][m4 * 4 + 0] = a4.x + b4.x;
            acc[pp][m4 * 4 + 1] = a4.y + b4.y;
            acc[pp][m4 * 4 + 2] = a4.z + b4.z;
            acc[pp][m4 * 4 + 3] = a4.w + b4.w;
        }
    }
    __syncthreads();                                // Pt built

    // --- K-chunked GEMM: acc[pp][m] += Pt[d][2pg+pp] * W[d][h0+m] ---
    for (int ch = 0; ch < 8; ++ch) {
        #pragma unroll
        for (int k = 0; k < 4; ++k) {
            int q = t + 256 * k;
            int dd = q >> 6, hh = (q & 63) * 4;
            *(float4*)&Wl[dd][hh] = wpre[k];
        }
        __syncthreads();
        if (ch < 7) {
            int d0n = (ch + 1) * DC2;
            #pragma unroll
            for (int k = 0; k < 4; ++k) {
                int q = t + 256 * k;
                int dd = q >> 6, hh = (q & 63) * 4;
                wpre[k] = *(const float4*)(Wc + (size_t)(d0n + dd) * H_ + hh);
            }
        }
        int d0 = ch * DC2;
        #pragma unroll
        for (int d = 0; d < DC2; ++d) {
            float2 pv = *(const float2*)&Pt[d0 + d][pg * 2];
            float wv[16];
            *(float4*)&wv[0]  = *(const float4*)&Wl[d][h0];
            *(float4*)&wv[4]  = *(const float4*)&Wl[d][h0 + 4];
            *(float4*)&wv[8]  = *(const float4*)&Wl[d][h0 + 8];
            *(float4*)&wv[12] = *(const float4*)&Wl[d][h0 + 12];
            #pragma unroll
            for (int m = 0; m < 16; ++m) {
                acc[0][m] = fmaf(pv.x, wv[m], acc[0][m]);
                acc[1][m] = fmaf(pv.y, wv[m], acc[1][m]);
            }
        }
        __syncthreads();
    }

    // --- epilogue: relu * W2, partial over this thread's 16 h ---
    {
        float w2v[16];
        *(float4*)&w2v[0]  = *(const float4*)(W2 + h0);
        *(float4*)&w2v[4]  = *(const float4*)(W2 + h0 + 4);
        *(float4*)&w2v[8]  = *(const float4*)(W2 + h0 + 8);
        *(float4*)&w2v[12] = *(const float4*)(W2 + h0 + 12);
        #pragma unroll
        for (int pp = 0; pp < 2; ++pp) {
            float sc = 0.f;
            #pragma unroll
            for (int m = 0; m < 16; ++m)
                sc = fmaf(fmaxf(acc[pp][m], 0.f), w2v[m], sc);
            part[pg * 2 + pp][hg] = sc;
        }
    }
    __syncthreads();
    if (t < 32) {
        float sum = b2[0];
        #pragma unroll
        for (int m = 0; m < 16; ++m) sum += part[t][m];
        rsc[t >> 4][t & 15] = sum;
    }
    __syncthreads();

    // top-8 among 16 exact scores, tiebreak smaller original index
    if (t < 32) {
        int rr = t >> 4, cc = t & 15;
        float my = rsc[rr][cc]; int myj = cand[rr][cc];
        int rank = 0;
        #pragma unroll
        for (int c2 = 0; c2 < 16; ++c2) {
            float o = rsc[rr][c2]; int oj = cand[rr][c2];
            rank += (o > my) || (o == my && oj < myj);
        }
        if (rank < 8) sel8[rr][rank] = myj;
    }
    __syncthreads();

    // gate / w
    for (int e = t; e < 512; e += 256) {
        int rr = e >> 8, jj = e & 255;
        float gv = 0.f;
        #pragma unroll
        for (int m = 0; m < 8; ++m)
            gv = (jj == sel8[rr][m]) ? 1.f : gv;
        gate[(size_t)(bi0 + rr) * N_ + jj] = gv;
        w[(size_t)(bi0 + rr) * N_ + jj]    = gv * 0.125f;
    }
    // ctx: 2 rows x 128 d
    {
        int rr = t >> 7, d = t & 127;
        float a = 0.f;
        #pragma unroll
        for (int m = 0; m < 8; ++m)
            a += s[((size_t)(b * N_ + sel8[rr][m])) * D_ + d];
        ctx[(size_t)(bi0 + rr) * D_ + d] = a * 0.125f;
    }
}

extern "C" void kernel_launch(void* const* d_in, const int* in_sizes, int n_in,
                              void* d_out, int out_size, void* d_ws, size_t ws_size,
                              hipStream_t stream)
{
    const float* s  = (const float*)d_in[0];
    const float* W1 = (const float*)d_in[1];
    const float* b1 = (const float*)d_in[2];
    const float* W2 = (const float*)d_in[3];
    const float* b2 = (const float*)d_in[4];

    float* avec = (float*)d_ws;                                           // 262144 f
    float* bvec = avec + (size_t)B_ * N_ * H_;                            // 262144 f
    unsigned short* ascu = (unsigned short*)(bvec + (size_t)B_ * N_ * H_);// 262144 us
    unsigned short* Wtu  = ascu + (size_t)B_ * N_ * N_;                   // 32768 us

    float* ctx  = (float*)d_out;
    float* gate = ctx + (size_t)B_ * N_ * D_;
    float* wout = gate + (size_t)B_ * N_ * N_;

    pre_kernel<<<384, 256, 0, stream>>>(s, W1, b1, avec, bvec, Wtu);
    approx_scores<<<256, 512, 0, stream>>>(s, Wtu, W2, b2, avec, bvec, ascu);
    finalize_kernel<<<B_ * N_ / 2, 256, 0, stream>>>(s, W1, W2, b2, avec, bvec, ascu,
                                                     ctx, gate, wout);
}

// Round 16
// 141.809 us; speedup vs baseline: 1.0518x; 1.0518x over previous
//
#include <hip/hip_runtime.h>
#include <hip/hip_bf16.h>
#include <math.h>

#define B_ 4
#define N_ 256
#define D_ 128
#define H_ 256
#define K_ 8

typedef __attribute__((ext_vector_type(8))) short short8;
typedef __attribute__((ext_vector_type(4))) float f32x4;

__device__ __forceinline__ unsigned short f2bf(float x) {
    union { __hip_bfloat16 h; unsigned short s; } u;
    u.h = __float2bfloat16(x);
    return u.s;
}
__device__ __forceinline__ float bf2f(unsigned short b) {
    unsigned v = ((unsigned)b) << 16;
    return __builtin_bit_cast(float, v);
}
__device__ __forceinline__ unsigned pk2(float x, float y) {
    union { __hip_bfloat162 h; unsigned u; } c;
    c.h = __float22bfloat162_rn(float2{x, y});
    return c.u;
}

// K0 v2: blocks 0..511: avec/bvec for 2 rows each, d-loop unrolled 8x
// (16 loads in flight — R15 accounting showed the old 256-block serial
// d-loop was a ~40 µs exposed-latency chain); blocks 512..639: Wt transpose.
__global__ __launch_bounds__(256) void pre_kernel(
    const float* __restrict__ s, const float* __restrict__ W1,
    const float* __restrict__ b1,
    float* __restrict__ avec, float* __restrict__ bvec,
    unsigned short* __restrict__ Wt)
{
    int blk = blockIdx.x;
    int t = threadIdx.x;
    if (blk < 512) {
        int bi0 = blk * 2;
        __shared__ float s2[2][D_];
        {
            int r = t >> 7, d = t & 127;   // 256 threads cover 2x128 exactly
            s2[r][d] = s[(size_t)(bi0 + r) * D_ + d];
        }
        __syncthreads();
        float aA0 = b1[t], aA1 = aA0, aB0 = 0.f, aB1 = 0.f;
        const float* W1a = W1 + t;
        const float* W1b = W1 + (size_t)D_ * H_ + t;
        #pragma unroll 8
        for (int d = 0; d < D_; ++d) {
            float wa = W1a[(size_t)d * H_];
            float wb = W1b[(size_t)d * H_];
            float s0 = s2[0][d], s1 = s2[1][d];
            aA0 = fmaf(s0, wa, aA0);
            aA1 = fmaf(s1, wa, aA1);
            aB0 = fmaf(s0, wb, aB0);
            aB1 = fmaf(s1, wb, aB1);
        }
        avec[(size_t)bi0 * H_ + t]       = aA0;
        avec[(size_t)(bi0 + 1) * H_ + t] = aA1;
        bvec[(size_t)bi0 * H_ + t]       = aB0;
        bvec[(size_t)(bi0 + 1) * H_ + t] = aB1;
    } else {
        int e = (blk - 512) * 256 + t;     // 32768 elements
        int h = e >> 7, d = e & 127;
        Wt[e] = f2bf(W1[(size_t)(2 * D_ + d) * H_ + h]);
    }
}

// K1 v4: block = (b, jt of 64 j, ic of 16 i). 256 blocks = 1/CU, 512 thr = 8 waves.
// (Unchanged — left the top-5.)
__global__ __launch_bounds__(512, 2) void approx_scores(
    const float* __restrict__ s, const unsigned short* __restrict__ Wt,
    const float* __restrict__ W2, const float* __restrict__ b2,
    const float* __restrict__ avec, const float* __restrict__ bvec,
    unsigned short* __restrict__ ascu)
{
    int blk = blockIdx.x;              // 256 = b(4) x jt(4) x ic(16)
    int b   = blk >> 6;
    int jtb = ((blk >> 4) & 3) * 64;
    int i0  = (blk & 15) * 16;
    int t = threadIdx.x;
    int lane = t & 63;
    int w = __builtin_amdgcn_readfirstlane(t >> 6);    // wave 0..7 -> 32-h slice
    int l15 = lane & 15, quad = lane >> 4;

    __shared__ __align__(16) short Pl[2][64 * 128];    // 32 KB (dbuf)
    __shared__ __align__(16) float si_all[16][D_];     // 8 KB
    __shared__ float partial[2][8][64];                // 4 KB

    const float* sB = s + (size_t)b * N_ * D_;

    {
        int ii = t >> 5, dq = t & 31;
        *(float4*)&si_all[ii][dq * 4] =
            *(const float4*)(sB + (size_t)(i0 + ii) * D_ + dq * 4);
    }

    short8 Wreg[2][4];
    #pragma unroll
    for (int mi = 0; mi < 2; ++mi)
        #pragma unroll
        for (int dk = 0; dk < 4; ++dk)
            Wreg[mi][dk] = *(const short8*)(
                Wt + (size_t)(w * 32 + mi * 16 + l15) * D_ + dk * 32 + quad * 8);
    float bvr[2][4][4];
    float w2r[2][4];
    #pragma unroll
    for (int mi = 0; mi < 2; ++mi) {
        int hq = w * 32 + mi * 16 + quad * 4;
        #pragma unroll
        for (int r = 0; r < 4; ++r)
            w2r[mi][r] = W2[hq + r];
        #pragma unroll
        for (int nj = 0; nj < 4; ++nj)
            #pragma unroll
            for (int r = 0; r < 4; ++r)
                bvr[mi][nj][r] = bvec[((size_t)(b * N_ + jtb + nj * 16 + l15)) * H_
                                      + hq + r];
    }
    float b2v = b2[0];
    __syncthreads();

    {
        int row = t >> 3, seg = t & 7;
        const float* sj = sB + (size_t)(jtb + row) * D_ + seg * 16;
        float4 a0 = ((const float4*)sj)[0], a1 = ((const float4*)sj)[1];
        float4 a2 = ((const float4*)sj)[2], a3 = ((const float4*)sj)[3];
        const float* si = &si_all[0][seg * 16];
        float4 s0 = ((const float4*)si)[0], s1 = ((const float4*)si)[1];
        float4 s2 = ((const float4*)si)[2], s3 = ((const float4*)si)[3];
        uint4 v0, v1;
        v0.x = pk2(a0.x * s0.x, a0.y * s0.y); v0.y = pk2(a0.z * s0.z, a0.w * s0.w);
        v0.z = pk2(a1.x * s1.x, a1.y * s1.y); v0.w = pk2(a1.z * s1.z, a1.w * s1.w);
        v1.x = pk2(a2.x * s2.x, a2.y * s2.y); v1.y = pk2(a2.z * s2.z, a2.w * s2.w);
        v1.z = pk2(a3.x * s3.x, a3.y * s3.y); v1.w = pk2(a3.z * s3.z, a3.w * s3.w);
        int pc0 = (seg * 2) ^ (row & 15), pc1 = (seg * 2 + 1) ^ (row & 15);
        *(uint4*)&Pl[0][row * 128 + pc0 * 8] = v0;
        *(uint4*)&Pl[0][row * 128 + pc1 * 8] = v1;
    }
    __syncthreads();

    #pragma unroll 1
    for (int i = 0; i < 16; ++i) {
        int cur = i & 1;
        if (w == 0 && i > 0) {
            float sum = b2v;
            #pragma unroll
            for (int ww = 0; ww < 8; ++ww) sum += partial[(i - 1) & 1][ww][lane];
            ascu[(size_t)(b * N_ + i0 + i - 1) * N_ + jtb + lane] = f2bf(sum);
        }
        float avc[2][4];
        #pragma unroll
        for (int mi = 0; mi < 2; ++mi) {
            int hq = w * 32 + mi * 16 + quad * 4;
            #pragma unroll
            for (int r = 0; r < 4; ++r)
                avc[mi][r] = avec[(size_t)(b * N_ + i0 + i) * H_ + hq + r];
        }
        f32x4 acc[2][4];
        #pragma unroll
        for (int mi = 0; mi < 2; ++mi)
            #pragma unroll
            for (int nj = 0; nj < 4; ++nj)
                acc[mi][nj] = (f32x4){0.f, 0.f, 0.f, 0.f};
        #pragma unroll
        for (int dk = 0; dk < 4; ++dk) {
            short8 Pf[4];
            #pragma unroll
            for (int nj = 0; nj < 4; ++nj) {
                int pcc = (dk * 4 + quad) ^ l15;
                Pf[nj] = *(const short8*)&Pl[cur][(nj * 16 + l15) * 128 + pcc * 8];
            }
            #pragma unroll
            for (int nj = 0; nj < 4; ++nj)
                #pragma unroll
                for (int mi = 0; mi < 2; ++mi)
                    acc[mi][nj] = __builtin_amdgcn_mfma_f32_16x16x32_bf16(
                        Wreg[mi][dk], Pf[nj], acc[mi][nj], 0, 0, 0);
        }
        if (i < 15) {
            int row = t >> 3, seg = t & 7;
            const float* sj = sB + (size_t)(jtb + row) * D_ + seg * 16;
            float4 a0 = ((const float4*)sj)[0], a1 = ((const float4*)sj)[1];
            float4 a2 = ((const float4*)sj)[2], a3 = ((const float4*)sj)[3];
            const float* si = &si_all[i + 1][seg * 16];
            float4 s0 = ((const float4*)si)[0], s1 = ((const float4*)si)[1];
            float4 s2 = ((const float4*)si)[2], s3 = ((const float4*)si)[3];
            uint4 v0, v1;
            v0.x = pk2(a0.x * s0.x, a0.y * s0.y); v0.y = pk2(a0.z * s0.z, a0.w * s0.w);
            v0.z = pk2(a1.x * s1.x, a1.y * s1.y); v0.w = pk2(a1.z * s1.z, a1.w * s1.w);
            v1.x = pk2(a2.x * s2.x, a2.y * s2.y); v1.y = pk2(a2.z * s2.z, a2.w * s2.w);
            v1.z = pk2(a3.x * s3.x, a3.y * s3.y); v1.w = pk2(a3.z * s3.z, a3.w * s3.w);
            int pc0 = (seg * 2) ^ (row & 15), pc1 = (seg * 2 + 1) ^ (row & 15);
            *(uint4*)&Pl[cur ^ 1][row * 128 + pc0 * 8] = v0;
            *(uint4*)&Pl[cur ^ 1][row * 128 + pc1 * 8] = v1;
        }
        float rs[4];
        #pragma unroll
        for (int nj = 0; nj < 4; ++nj) rs[nj] = 0.f;
        #pragma unroll
        for (int mi = 0; mi < 2; ++mi)
            #pragma unroll
            for (int nj = 0; nj < 4; ++nj)
                #pragma unroll
                for (int r = 0; r < 4; ++r) {
                    float z = acc[mi][nj][r] + avc[mi][r] + bvr[mi][nj][r];
                    rs[nj] = fmaf(fmaxf(z, 0.f), w2r[mi][r], rs[nj]);
                }
        #pragma unroll
        for (int nj = 0; nj < 4; ++nj) {
            rs[nj] += __shfl_xor(rs[nj], 16);
            rs[nj] += __shfl_xor(rs[nj], 32);
        }
        float v = (quad == 0) ? rs[0] : (quad == 1) ? rs[1] : (quad == 2) ? rs[2] : rs[3];
        partial[cur][w][lane] = v;
        __syncthreads();
    }
    if (w == 0) {
        float sum = b2v;
        #pragma unroll
        for (int ww = 0; ww < 8; ++ww) sum += partial[15 & 1][ww][lane];
        ascu[(size_t)(b * N_ + i0 + 15) * N_ + jtb + lane] = f2bf(sum);
    }
}

// K2: reverted to R12's measured-fastest config (512 thr, (512,4), DCH=32,
// 44 µs). Five rounds of allocator knobs (R11-R15) bracketed finalize at
// 44-50 µs; 512-thr variants win despite scratch traffic. Closing this line.
#define DCH 32
__global__ __launch_bounds__(512, 4) void finalize_kernel(
    const float* __restrict__ s, const float* __restrict__ W1,
    const float* __restrict__ W2, const float* __restrict__ b2,
    const float* __restrict__ avec, const float* __restrict__ bvec,
    const unsigned short* __restrict__ ascu,
    float* __restrict__ ctx, float* __restrict__ gate, float* __restrict__ w)
{
    int bi0 = blockIdx.x * 2;          // 512 blocks
    int b = bi0 >> 8;
    int t = threadIdx.x;               // 0..511

    __shared__ float asc[2][N_];
    __shared__ int cand[2][16];
    __shared__ __align__(16) float Pt[D_][32];
    __shared__ __align__(16) float Wl[DCH][H_];
    __shared__ float part[32][33];
    __shared__ float rsc[2][16];
    __shared__ int sel8[2][8];

    {
        int tr = t >> 8, jj = t & 255;
        asc[tr][jj] = bf2f(ascu[(size_t)(bi0 + tr) * N_ + jj]);
    }
    __syncthreads();
    {
        int tr = t >> 8, jj = t & 255;
        float my = asc[tr][jj];
        int rank = 0;
        #pragma unroll 8
        for (int j2 = 0; j2 < N_; ++j2) {
            float o = asc[tr][j2];
            rank += (o > my) || (o == my && j2 < jj);
        }
        if (rank < 16) cand[tr][rank] = jj;
    }
    __syncthreads();

    const float* Wc = W1 + (size_t)2 * D_ * H_;

    float4 wpre[4];
    #pragma unroll
    for (int k = 0; k < 4; ++k) {
        int q = t + 512 * k;
        int dd = q >> 6, hh = (q & 63) * 4;
        wpre[k] = *(const float4*)(Wc + (size_t)dd * H_ + hh);
    }

    #pragma unroll
    for (int e = t; e < 1024; e += 512) {
        int p = e & 31, dq = e >> 5;
        int r = p >> 4, c = p & 15;
        int j = cand[r][c];
        float4 sj = *(const float4*)(s + ((size_t)(b * N_ + j)) * D_ + dq * 4);
        float4 si = *(const float4*)(s + ((size_t)(bi0 + r)) * D_ + dq * 4);
        Pt[dq * 4 + 0][p] = si.x * sj.x;
        Pt[dq * 4 + 1][p] = si.y * sj.y;
        Pt[dq * 4 + 2][p] = si.z * sj.z;
        Pt[dq * 4 + 3][p] = si.w * sj.w;
    }

    int pg = t & 15, hg = t >> 4;
    int h0 = hg * 8;
    float acc[2][8];
    #pragma unroll
    for (int pp = 0; pp < 2; ++pp) {
        int p = pg * 2 + pp;
        int r = p >> 4, c = p & 15;
        int j = cand[r][c];
        const float* av = avec + (size_t)(bi0 + r) * H_ + h0;
        const float* bv = bvec + ((size_t)(b * N_ + j)) * H_ + h0;
        #pragma unroll
        for (int m4 = 0; m4 < 2; ++m4) {
            float4 a4 = *(const float4*)(av + m4 * 4);
            float4 b4 = *(const float4*)(bv + m4 * 4);
            acc[pp][m4 * 4 + 0] = a4.x + b4.x;
            acc[pp][m4 * 4 + 1] = a4.y + b4.y;
            acc[pp][m4 * 4 + 2] = a4.z + b4.z;
            acc[pp][m4 * 4 + 3] = a4.w + b4.w;
        }
    }
    __syncthreads();

    for (int ch = 0; ch < 4; ++ch) {
        #pragma unroll
        for (int k = 0; k < 4; ++k) {
            int q = t + 512 * k;
            int dd = q >> 6, hh = (q & 63) * 4;
            *(float4*)&Wl[dd][hh] = wpre[k];
        }
        __syncthreads();
        if (ch < 3) {
            int d0n = (ch + 1) * DCH;
            #pragma unroll
            for (int k = 0; k < 4; ++k) {
                int q = t + 512 * k;
                int dd = q >> 6, hh = (q & 63) * 4;
                wpre[k] = *(const float4*)(Wc + (size_t)(d0n + dd) * H_ + hh);
            }
        }
        int d0 = ch * DCH;
        #pragma unroll
        for (int d = 0; d < DCH; ++d) {
            float2 pv = *(const float2*)&Pt[d0 + d][pg * 2];
            float wv[8];
            *(float4*)&wv[0] = *(const float4*)&Wl[d][h0];
            *(float4*)&wv[4] = *(const float4*)&Wl[d][h0 + 4];
            #pragma unroll
            for (int m = 0; m < 8; ++m) {
                acc[0][m] = fmaf(pv.x, wv[m], acc[0][m]);
                acc[1][m] = fmaf(pv.y, wv[m], acc[1][m]);
            }
        }
        __syncthreads();
    }

    {
        float w2v[8];
        *(float4*)&w2v[0] = *(const float4*)(W2 + h0);
        *(float4*)&w2v[4] = *(const float4*)(W2 + h0 + 4);
        #pragma unroll
        for (int pp = 0; pp < 2; ++pp) {
            float sc = 0.f;
            #pragma unroll
            for (int m = 0; m < 8; ++m)
                sc = fmaf(fmaxf(acc[pp][m], 0.f), w2v[m], sc);
            part[pg * 2 + pp][hg] = sc;
        }
    }
    __syncthreads();
    if (t < 32) {
        float sum = b2[0];
        #pragma unroll
        for (int m = 0; m < 32; ++m) sum += part[t][m];
        rsc[t >> 4][t & 15] = sum;
    }
    __syncthreads();

    if (t < 32) {
        int rr = t >> 4, cc = t & 15;
        float my = rsc[rr][cc]; int myj = cand[rr][cc];
        int rank = 0;
        #pragma unroll
        for (int c2 = 0; c2 < 16; ++c2) {
            float o = rsc[rr][c2]; int oj = cand[rr][c2];
            rank += (o > my) || (o == my && oj < myj);
        }
        if (rank < 8) sel8[rr][rank] = myj;
    }
    __syncthreads();

    {
        int rr = t >> 8, jj = t & 255;
        float gv = 0.f;
        #pragma unroll
        for (int m = 0; m < 8; ++m)
            gv = (jj == sel8[rr][m]) ? 1.f : gv;
        gate[(size_t)(bi0 + rr) * N_ + jj] = gv;
        w[(size_t)(bi0 + rr) * N_ + jj]    = gv * 0.125f;
    }
    if (t < 256) {
        int rr = t >> 7, d = t & 127;
        float a = 0.f;
        #pragma unroll
        for (int m = 0; m < 8; ++m)
            a += s[((size_t)(b * N_ + sel8[rr][m])) * D_ + d];
        ctx[(size_t)(bi0 + rr) * D_ + d] = a * 0.125f;
    }
}

extern "C" void kernel_launch(void* const* d_in, const int* in_sizes, int n_in,
                              void* d_out, int out_size, void* d_ws, size_t ws_size,
                              hipStream_t stream)
{
    const float* s  = (const float*)d_in[0];
    const float* W1 = (const float*)d_in[1];
    const float* b1 = (const float*)d_in[2];
    const float* W2 = (const float*)d_in[3];
    const float* b2 = (const float*)d_in[4];

    float* avec = (float*)d_ws;                                           // 262144 f
    float* bvec = avec + (size_t)B_ * N_ * H_;                            // 262144 f
    unsigned short* ascu = (unsigned short*)(bvec + (size_t)B_ * N_ * H_);// 262144 us
    unsigned short* Wtu  = ascu + (size_t)B_ * N_ * N_;                   // 32768 us

    float* ctx  = (float*)d_out;
    float* gate = ctx + (size_t)B_ * N_ * D_;
    float* wout = gate + (size_t)B_ * N_ * N_;

    pre_kernel<<<640, 256, 0, stream>>>(s, W1, b1, avec, bvec, Wtu);
    approx_scores<<<256, 512, 0, stream>>>(s, Wtu, W2, b2, avec, bvec, ascu);
    finalize_kernel<<<B_ * N_ / 2, 512, 0, stream>>>(s, W1, W2, b2, avec, bvec, ascu,
                                                     ctx, gate, wout);
}